// Round 7
// baseline (4046.896 us; speedup 1.0000x reference)
//
// Seq2Seq BiLSTM (B=256,T=96,D=64,H=256,L=5, dec H2=512, P=14) — round 7.
// vs r6: enc_layer sync rewritten to SELF-VALIDATING TAGGED h (u32 = f16|tag)
// published via relaxed agent u64 stores. Kills 2 of 3 per-step L3 round
// trips: no vmcnt publish-ack, no flag store/poll — consumer polls its own
// A-frag words until tags match, strips tags in-register. Parity-2 overwrite
// provably race-free (publish(t+1) => consumed(t)). Weights stay LDS-resident
// (r6 win). dec_step/gemm_xg/fc unchanged; prep drops flag init.
#include <hip/hip_runtime.h>

typedef _Float16 f16;
using half8 = __attribute__((ext_vector_type(8))) _Float16;
using half4 = __attribute__((ext_vector_type(4))) _Float16;
using f32x4 = __attribute__((ext_vector_type(4))) float;

#define DEV __device__ __forceinline__
#define LD8(p) (*(const half8*)(const void*)(p))

DEV f32x4 mfma16(half8 a, half8 b, f32x4 c) {
  return __builtin_amdgcn_mfma_f32_16x16x32_f16(a, b, c, 0, 0, 0);
}
DEV float sigf(float x) { return 1.f / (1.f + __expf(-x)); }
DEV float tanhf2(float x) { float e = __expf(2.f * x); return 1.f - 2.f / (e + 1.f); }

// ---- workspace layout (byte offsets, all 256-aligned; total ~194 MB) ----
static const size_t OFF_WIH0   = 0;          // [2][1024][64] f16
static const size_t OFF_WIH14  = 262144;     // [4][2][1024][512] f16
static const size_t OFF_WHH    = 8650752;    // frag-major [5][d][uo8][tile2][g4][kc8][ln64][e8] f16
static const size_t OFF_WDEC0  = 13893632;   // [2048][576] f16 ([Wih|Whh])
static const size_t OFF_WDEC14 = 16252928;   // [4][2048][1024] f16
static const size_t OFF_WFC    = 33030144;   // [64][512] f16
static const size_t OFF_X16    = 33095680;   // [96][256][64] f16
static const size_t OFF_SEQA   = 36241408;   // [96][256][512] f16
static const size_t OFF_SEQB   = 61407232;   // [96][256][512] f16
static const size_t OFF_XG     = 86573056;   // frag-major [2][1536][64][64][4] f16
static const size_t OFF_HBUF   = 187236352;  // tagged [16bb][2d][2par][16][256] u32 (1 MB)
static const size_t OFF_DHDB   = 188284928;  // [2][5][256][512] f16 (parity,layer)
static const size_t OFF_DCST   = 190906368;  // [5][256][512] f32
static const size_t OFF_ZFC    = 193527808;  // [256][512] f16 (cols 0..63 used)

// ---------------- prep: convert/pack weights + x to f16 -------------------
__global__ __launch_bounds__(256) void prep(
    const float* __restrict__ x,
    const float* __restrict__ eWih0, const float* __restrict__ eWhh0,
    const float* __restrict__ eWih,  const float* __restrict__ eWhh,
    const float* __restrict__ dWih0, const float* __restrict__ dWhh0,
    const float* __restrict__ dWih,  const float* __restrict__ dWhh,
    const float* __restrict__ fcW,   char* __restrict__ ws)
{
  f16* wih0   = (f16*)(ws + OFF_WIH0);
  f16* wih14  = (f16*)(ws + OFF_WIH14);
  f16* whhf   = (f16*)(ws + OFF_WHH);
  f16* wdec0  = (f16*)(ws + OFF_WDEC0);
  f16* wdec14 = (f16*)(ws + OFF_WDEC14);
  f16* wfc    = (f16*)(ws + OFF_WFC);
  f16* x16    = (f16*)(ws + OFF_X16);
  f16* zfc    = (f16*)(ws + OFF_ZFC);
  const size_t total = 18137088;
  for (size_t i = (size_t)blockIdx.x * blockDim.x + threadIdx.x; i < total;
       i += (size_t)gridDim.x * blockDim.x) {
    size_t j = i;
    if (j < 131072) { wih0[j] = (f16)eWih0[j]; continue; }
    j -= 131072;
    if (j < 4194304) { wih14[j] = (f16)eWih[j]; continue; }
    j -= 4194304;
    if (j < 2621440) {  // Whh -> frag-major 8-way-split layout (dest linear=j)
      size_t l = j >> 19, i2 = j & 524287;
      int d   = (int)(i2 >> 18);
      int uo  = (int)((i2 >> 15) & 7);
      int tile= (int)((i2 >> 14) & 1);
      int g   = (int)((i2 >> 12) & 3);
      int kc  = (int)((i2 >> 9) & 7);
      int lnv = (int)((i2 >> 3) & 63);
      int e   = (int)(i2 & 7);
      int unit = uo * 32 + tile * 16 + (lnv & 15);
      int k = kc * 32 + (lnv >> 4) * 8 + e;
      int row = g * 256 + unit;
      float v = (l == 0) ? eWhh0[((size_t)d * 1024 + row) * 256 + k]
                         : eWhh[((((l - 1) * 2 + (size_t)d) * 1024) + row) * 256 + k];
      whhf[j] = (f16)v;
      continue;
    }
    j -= 2621440;
    if (j < 1179648) {  // dec layer0: [2048][64|512] -> [2048][576]
      size_t r = j / 576, c = j % 576;
      wdec0[j] = (f16)((c < 64) ? dWih0[r * 64 + c] : dWhh0[r * 512 + (c - 64)]);
      continue;
    }
    j -= 1179648;
    if (j < 8388608) {  // dec layers1-4: [2048][512|512] -> [2048][1024]
      size_t l = j >> 21, rem = j & 2097151;
      size_t r = rem >> 10, c = rem & 1023;
      wdec14[j] = (f16)((c < 512) ? dWih[(l * 2048 + r) * 512 + c]
                                  : dWhh[(l * 2048 + r) * 512 + (c - 512)]);
      continue;
    }
    j -= 8388608;
    if (j < 32768) { wfc[j] = (f16)fcW[j]; continue; }
    j -= 32768;
    if (j < 1572864) {  // x (B,T,D) -> x16 [t][b][d]
      size_t t = j >> 14, rem = j & 16383;
      size_t b = rem >> 6, d = rem & 63;
      x16[j] = (f16)x[(b * 96 + t) * 64 + d];
      continue;
    }
    j -= 1572864;
    {  // decoder first input = x[:, -1, :]
      size_t b = j >> 6, d = j & 63;
      zfc[b * 512 + d] = (f16)x[(b * 96 + 95) * 64 + d];
    }
  }
}

// ------------- phase A: Xg[dir][t,b][4H] = in @ Wih^T + (bih+bhh) ---------
__global__ __launch_bounds__(256) void gemm_xg(
    const f16* __restrict__ A, int K, const f16* __restrict__ W,
    const float* __restrict__ bih, const float* __restrict__ bhh,
    f16* __restrict__ xg)
{
  __shared__ __align__(16) f16 As[128 * 32];
  __shared__ __align__(16) f16 Ws[128 * 32];
  const int dir = blockIdx.y >> 3;
  const int cb  = (blockIdx.y & 7) * 128;
  const int rb  = blockIdx.x * 128;
  const int tid = threadIdx.x;
  const int wv = tid >> 6, ln = tid & 63;
  const int wr = wv >> 1, wc = wv & 1;
  const f16* Wd = W + (size_t)dir * 1024 * K;

  f32x4 acc[4][4];
#pragma unroll
  for (int m = 0; m < 4; m++)
#pragma unroll
    for (int n = 0; n < 4; n++) acc[m][n] = (f32x4){0.f, 0.f, 0.f, 0.f};

  const int sr = tid >> 1;
  const int sk = (tid & 1) * 16;
  const int nk = K >> 5;
  for (int kt = 0; kt < nk; ++kt) {
    half8 va0 = LD8(&A[(size_t)(rb + sr) * K + kt * 32 + sk]);
    half8 va1 = LD8(&A[(size_t)(rb + sr) * K + kt * 32 + sk + 8]);
    half8 vw0 = LD8(&Wd[(size_t)(cb + sr) * K + kt * 32 + sk]);
    half8 vw1 = LD8(&Wd[(size_t)(cb + sr) * K + kt * 32 + sk + 8]);
    *(half8*)&As[sr * 32 + sk] = va0;
    *(half8*)&As[sr * 32 + sk + 8] = va1;
    *(half8*)&Ws[sr * 32 + sk] = vw0;
    *(half8*)&Ws[sr * 32 + sk + 8] = vw1;
    __syncthreads();
    half8 af[4], bf[4];
#pragma unroll
    for (int m = 0; m < 4; m++)
      af[m] = LD8(&As[(wr * 64 + m * 16 + (ln & 15)) * 32 + (ln >> 4) * 8]);
#pragma unroll
    for (int n = 0; n < 4; n++)
      bf[n] = LD8(&Ws[(wc * 64 + n * 16 + (ln & 15)) * 32 + (ln >> 4) * 8]);
#pragma unroll
    for (int m = 0; m < 4; m++)
#pragma unroll
      for (int n = 0; n < 4; n++) acc[m][n] = mfma16(af[m], bf[n], acc[m][n]);
    __syncthreads();
  }
#pragma unroll
  for (int n = 0; n < 4; n++) {
    const int col = cb + wc * 64 + n * 16 + (ln & 15);
    const float bsum = bih[dir * 1024 + col] + bhh[dir * 1024 + col];
    const int c16 = (cb + wc * 64 + n * 16) >> 4;
#pragma unroll
    for (int m = 0; m < 4; m++) {
      const int r16 = (rb + wr * 64 + m * 16) >> 4;
      half4 h;
#pragma unroll
      for (int r = 0; r < 4; r++) h[r] = (f16)(acc[m][n][r] + bsum);
      *(half4*)&xg[(((size_t)dir * 1536 + r16) * 64 + c16) * 256 + ln * 4] = h;
    }
  }
}

// --------- persistent encoder layer v5: tagged-h single-RT sync -----------
// grid (16,16): x=bb, y=d*8+uo. 128 thr / 2 waves. Whh (64 KB) LDS-resident.
// h published as tagged u32 (f16 | tag<<16), tag=layer*96+t, via relaxed
// agent u64 stores (fire-and-forget). Consumer polls its own 32 A-frag u64s
// until all tags match, strips tags in-register. No flags, no vmcnt drain.
__global__ __launch_bounds__(128) void enc_layer(
    const f16* __restrict__ xg, const f16* __restrict__ whhf,
    unsigned* __restrict__ hbuf,
    f16* __restrict__ seqo, f16* __restrict__ hfin, float* __restrict__ cfin,
    int layer)
{
  const int bb = blockIdx.x;
  const int d = blockIdx.y >> 3, uo = blockIdx.y & 7;
  const int tid = threadIdx.x;
  const int wv = tid >> 6, ln = tid & 63;
  const int lc = ln & 15, lk = ln >> 4;

  __shared__ __align__(16) f16 wL[32768];   // [tile2][g4][kc8][ln64][e8] 64 KB
  __shared__ __align__(16) f16 hB[16 * 36]; // bounce, row stride 36

  // one-time weight stage: 64 KB global -> LDS, coalesced half8 copies
  const f16* wsrc = whhf + (size_t)(d * 8 + uo) * 32768;
#pragma unroll 4
  for (int i = 0; i < 32; i++)
    *(half8*)&wL[(i * 128 + tid) * 8] = LD8(&wsrc[(size_t)(i * 128 + tid) * 8]);
  __syncthreads();

  unsigned* hbase = hbuf + (size_t)(bb * 2 + d) * 8192;  // [2par][16][256] u32
  const int base = layer * 96;
  const int rowbase = bb * 16;
  const int cu = uo * 32 + wv * 16 + lc;      // global unit of lane
  const int erow = tid >> 3, e4 = (tid & 7) * 4;  // export: 4 units/thread

  f32x4 cst = (f32x4){0.f, 0.f, 0.f, 0.f};

  for (int t = 0; t < 96; ++t) {
    const int tt = d ? 95 - t : t;
    const int par = (t - 1) & 1, par2 = t & 1;
    const int r16 = tt * 16 + bb;
    // xg loads issue first (independent of sync)
    half4 xv[4];
#pragma unroll
    for (int g = 0; g < 4; g++)
      xv[g] = *(const half4*)&xg[(((size_t)d * 1536 + r16) * 64 +
                                  (g * 16 + uo * 2 + wv)) * 256 + ln * 4];
    f32x4 acc[4];
#pragma unroll
    for (int g = 0; g < 4; g++)
      acc[g] = (f32x4){(float)xv[g][0], (float)xv[g][1],
                       (float)xv[g][2], (float)xv[g][3]};

    if (t > 0) {
      // per-lane poll of the 32 tagged u64s this lane's A-frags need
      const unsigned tagexp = (unsigned)(base + t - 1);
      const unsigned long long* hrow = (const unsigned long long*)
          (hbase + ((size_t)par * 16 + lc) * 256);
      unsigned long long q[32];
      unsigned spin = 0;
      bool ok;
      do {
        ok = true;
#pragma unroll
        for (int j = 0; j < 8; j++) {
          const unsigned long long* p = hrow + (j * 32 + lk * 8) / 2;
#pragma unroll
          for (int m = 0; m < 4; m++) {
            q[j * 4 + m] = __hip_atomic_load(p + m, __ATOMIC_RELAXED,
                                             __HIP_MEMORY_SCOPE_AGENT);
            ok = ok && ((((unsigned)q[j * 4 + m]) >> 16) == tagexp);
          }
        }
      } while (!ok && ++spin < 50000u);  // tripwire: no hang, wrong answer
      // strip tags -> half8 A-frags, MFMA against LDS-resident weights
#pragma unroll
      for (int j = 0; j < 8; j++) {
        union { unsigned w[4]; half8 h; } u;
#pragma unroll
        for (int m = 0; m < 4; m++) {
          unsigned long long qq = q[j * 4 + m];
          u.w[m] = ((unsigned)qq & 0xFFFFu) |
                   ((((unsigned)(qq >> 32)) & 0xFFFFu) << 16);
        }
#pragma unroll
        for (int g = 0; g < 4; g++) {
          half8 b = *(const half8*)&wL[(size_t)(((wv * 4 + g) * 8 + j) * 64 + ln) * 8];
          acc[g] = mfma16(u.h, b, acc[g]);
        }
      }
    }
    // LSTM cell, fully in registers (lane owns 4 rows x 1 unit)
    f16 hv[4];
#pragma unroll
    for (int r = 0; r < 4; r++) {
      float gi = sigf(acc[0][r]);
      float gf = sigf(acc[1][r]);
      float gg = tanhf2(acc[2][r]);
      float go = sigf(acc[3][r]);
      float cn = gf * cst[r] + gi * gg;
      cst[r] = cn;
      hv[r] = (f16)(go * tanhf2(cn));
    }
    // bounce to LDS (de-swizzled layout, stride 36)
#pragma unroll
    for (int r = 0; r < 4; r++)
      hB[(lk * 4 + r) * 36 + wv * 16 + lc] = hv[r];
    __syncthreads();  // B1: bounce complete
    // export: tagged h (fire-and-forget) + clean seqo
    {
      const unsigned tagv = (unsigned)(base + t) << 16;
      unsigned long long v = *(const unsigned long long*)&hB[erow * 36 + e4];
      unsigned lo = (unsigned)v, hi = (unsigned)(v >> 32);
      unsigned long long t0 = (unsigned long long)((lo & 0xFFFFu) | tagv) |
                              ((unsigned long long)((lo >> 16) | tagv) << 32);
      unsigned long long t1 = (unsigned long long)((hi & 0xFFFFu) | tagv) |
                              ((unsigned long long)((hi >> 16) | tagv) << 32);
      unsigned* hdst = hbase + ((size_t)par2 * 16 + erow) * 256 + uo * 32 + e4;
      __hip_atomic_store((unsigned long long*)hdst, t0,
                         __ATOMIC_RELAXED, __HIP_MEMORY_SCOPE_AGENT);
      __hip_atomic_store((unsigned long long*)(hdst + 2), t1,
                         __ATOMIC_RELAXED, __HIP_MEMORY_SCOPE_AGENT);
      *(unsigned long long*)&seqo[(size_t)tt * 131072 +
          (size_t)(rowbase + erow) * 512 + d * 256 + uo * 32 + e4] = v;
      if (t == 95) {
        *(unsigned long long*)&hfin[(size_t)(rowbase + erow) * 512 +
                                    d * 256 + uo * 32 + e4] = v;
#pragma unroll
        for (int r = 0; r < 4; r++)
          cfin[(size_t)(rowbase + lk * 4 + r) * 512 + d * 256 + cu] = cst[r];
      }
    }
    __syncthreads();  // B2: exports done before hB rewrite (no drain needed)
  }
}

// --------- decoder: one layer-eval; WG = 4 row-blocks x 32 units ----------
__global__ __launch_bounds__(128) void dec_step(
    const f16* __restrict__ A0, int K0, const f16* __restrict__ A1,
    const f16* __restrict__ W, int Kt,
    const float* __restrict__ bih, const float* __restrict__ bhh,
    float* __restrict__ cst, f16* __restrict__ h1)
{
  const int u0 = blockIdx.y * 32;
  const int rb = blockIdx.x * 64;
  const int wv = threadIdx.x >> 6, ln = threadIdx.x & 63;
  const int lc = ln & 15, lk = ln >> 4;
  const int cu = u0 + wv * 16 + lc;  // unit 0..511
  f32x4 acc[4][4];  // [rr][g]
#pragma unroll
  for (int g = 0; g < 4; g++) {
    float b = bih[g * 512 + cu] + bhh[g * 512 + cu];
#pragma unroll
    for (int rr = 0; rr < 4; rr++) acc[rr][g] = (f32x4){b, b, b, b};
  }
  const int K0c = K0 >> 5, Ktc = Kt >> 5;
  for (int kc = 0; kc < Ktc; kc++) {
    const f16* Ap; int ko;
    if (kc < K0c) { Ap = A0; ko = kc * 32; }
    else          { Ap = A1; ko = (kc - K0c) * 32; }
    half8 b[4];
#pragma unroll
    for (int g = 0; g < 4; g++)
      b[g] = LD8(&W[(size_t)(g * 512 + cu) * Kt + kc * 32 + lk * 8]);
#pragma unroll
    for (int rr = 0; rr < 4; rr++) {
      half8 a = LD8(&Ap[(size_t)(rb + rr * 16 + lc) * 512 + ko + lk * 8]);
#pragma unroll
      for (int g = 0; g < 4; g++) acc[rr][g] = mfma16(a, b[g], acc[rr][g]);
    }
  }
#pragma unroll
  for (int rr = 0; rr < 4; rr++) {
#pragma unroll
    for (int r = 0; r < 4; r++) {
      const int row = rb + rr * 16 + lk * 4 + r;
      float gi = sigf(acc[rr][0][r]);
      float gf = sigf(acc[rr][1][r]);
      float gg = tanhf2(acc[rr][2][r]);
      float go = sigf(acc[rr][3][r]);
      float cp = cst[(size_t)row * 512 + cu];
      float cn = gf * cp + gi * gg;
      cst[(size_t)row * 512 + cu] = cn;
      h1[(size_t)row * 512 + cu] = (f16)(go * tanhf2(cn));
    }
  }
}

// --------- FC: out = h4 @ fcW^T + b; writes d_out slice + feedback --------
__global__ __launch_bounds__(64) void fc_kernel(
    const f16* __restrict__ hin, const f16* __restrict__ Wf,
    const float* __restrict__ bf, float* __restrict__ out,
    f16* __restrict__ zfc, int s)
{
  const int rb = blockIdx.x * 16;
  const int ln = threadIdx.x;
  f32x4 acc[4];
#pragma unroll
  for (int n = 0; n < 4; n++) acc[n] = (f32x4){0.f, 0.f, 0.f, 0.f};
#pragma unroll
  for (int kc = 0; kc < 16; kc++) {
    half8 a = LD8(&hin[(size_t)(rb + (ln & 15)) * 512 + kc * 32 + (ln >> 4) * 8]);
#pragma unroll
    for (int n = 0; n < 4; n++) {
      half8 b = LD8(&Wf[(size_t)(n * 16 + (ln & 15)) * 512 + kc * 32 + (ln >> 4) * 8]);
      acc[n] = mfma16(a, b, acc[n]);
    }
  }
#pragma unroll
  for (int n = 0; n < 4; n++) {
    const int col = n * 16 + (ln & 15);
    const float bb = bf[col];
#pragma unroll
    for (int r = 0; r < 4; r++) {
      const int row = rb + (ln >> 4) * 4 + r;
      float v = acc[n][r] + bb;
      out[(size_t)row * 896 + s * 64 + col] = v;
      zfc[(size_t)row * 512 + col] = (f16)v;
    }
  }
}

extern "C" void kernel_launch(void* const* d_in, const int* in_sizes, int n_in,
                              void* d_out, int out_size, void* d_ws, size_t ws_size,
                              hipStream_t stream) {
  char* ws = (char*)d_ws;
  const float* x     = (const float*)d_in[0];
  const float* eWih0 = (const float*)d_in[1];
  const float* eWhh0 = (const float*)d_in[2];
  const float* ebih0 = (const float*)d_in[3];
  const float* ebhh0 = (const float*)d_in[4];
  const float* eWih  = (const float*)d_in[5];
  const float* eWhh  = (const float*)d_in[6];
  const float* ebih  = (const float*)d_in[7];
  const float* ebhh  = (const float*)d_in[8];
  const float* dWih0 = (const float*)d_in[9];
  const float* dWhh0 = (const float*)d_in[10];
  const float* dbih0 = (const float*)d_in[11];
  const float* dbhh0 = (const float*)d_in[12];
  const float* dWih  = (const float*)d_in[13];
  const float* dWhh  = (const float*)d_in[14];
  const float* dbih  = (const float*)d_in[15];
  const float* dbhh  = (const float*)d_in[16];
  const float* fcW   = (const float*)d_in[17];
  const float* fcb   = (const float*)d_in[18];

  f16* xg    = (f16*)(ws + OFF_XG);
  unsigned* hbuf = (unsigned*)(ws + OFF_HBUF);
  f16* dhdb  = (f16*)(ws + OFF_DHDB);
  float* dcst = (float*)(ws + OFF_DCST);
  f16* zfc   = (f16*)(ws + OFF_ZFC);
  f16* seqA  = (f16*)(ws + OFF_SEQA);
  f16* seqB  = (f16*)(ws + OFF_SEQB);

  prep<<<dim3(2048), dim3(256), 0, stream>>>(x, eWih0, eWhh0, eWih, eWhh,
                                             dWih0, dWhh0, dWih, dWhh, fcW, ws);

  // ---------------- encoder ----------------
  for (int l = 0; l < 5; ++l) {
    const f16* Ain = (l == 0) ? (f16*)(ws + OFF_X16) : ((l & 1) ? seqA : seqB);
    const int K = (l == 0) ? 64 : 512;
    const f16* Wih = (l == 0) ? (f16*)(ws + OFF_WIH0)
                              : (f16*)(ws + OFF_WIH14) + (size_t)(l - 1) * 2 * 1024 * 512;
    const float* bi = (l == 0) ? ebih0 : ebih + (size_t)(l - 1) * 2048;
    const float* bh = (l == 0) ? ebhh0 : ebhh + (size_t)(l - 1) * 2048;
    gemm_xg<<<dim3(192, 16), dim3(256), 0, stream>>>(Ain, K, Wih, bi, bh, xg);

    const f16* whhf_l = (f16*)(ws + OFF_WHH) + (size_t)l * 524288;
    f16* so = (l & 1) ? seqB : seqA;
    enc_layer<<<dim3(16, 16), dim3(128), 0, stream>>>(
        xg, whhf_l, hbuf, so,
        dhdb + (size_t)l * 131072, dcst + (size_t)l * 131072, l);
  }

  // ---------------- decoder ----------------
  for (int s = 0; s < 14; ++s) {
    const int p = s & 1;
    for (int l = 0; l < 5; ++l) {
      dec_step<<<dim3(4, 16), dim3(128), 0, stream>>>(
          (l == 0) ? zfc : dhdb + (size_t)(p ^ 1) * 655360 + (size_t)(l - 1) * 131072,
          (l == 0) ? 64 : 512,
          dhdb + (size_t)p * 655360 + (size_t)l * 131072,
          (l == 0) ? (f16*)(ws + OFF_WDEC0)
                   : (f16*)(ws + OFF_WDEC14) + (size_t)(l - 1) * 2048 * 1024,
          (l == 0) ? 576 : 1024,
          (l == 0) ? dbih0 : dbih + (size_t)(l - 1) * 2048,
          (l == 0) ? dbhh0 : dbhh + (size_t)(l - 1) * 2048,
          dcst + (size_t)l * 131072,
          dhdb + (size_t)(p ^ 1) * 655360 + (size_t)l * 131072);
    }
    fc_kernel<<<dim3(16), dim3(64), 0, stream>>>(
        dhdb + (size_t)(p ^ 1) * 655360 + 4 * 131072, (f16*)(ws + OFF_WFC), fcb,
        (float*)d_out, zfc, s);
  }
}